// Round 1
// baseline (8669.302 us; speedup 1.0000x reference)
//
#include <hip/hip_runtime.h>
#include <math.h>

#define N 64
#define S 65  // LDS row stride (pad +1: all row/col per-lane patterns are 2-way = free)
#define MAX_ITER 5

// One 64-thread wave per 64x64 matrix.
// LDS: A (work matrix -> R), Q (per-iteration Q), Qt (accumulated Q_total).
// Householder QR, sign convention alpha = -sign(x0)*||x|| (washes out of final X).
__global__ __launch_bounds__(64) void logm_kernel(const float* __restrict__ gin,
                                                  float* __restrict__ gout) {
    __shared__ float A[N * S];
    __shared__ float Q[N * S];
    __shared__ float Qt[N * S];
    __shared__ float v[N];
    __shared__ float sm[N];

    const int t = threadIdx.x;
    const long b = blockIdx.x;
    const float* __restrict__ in = gin + b * (long)(N * N);
    float* __restrict__ out = gout + b * (long)(N * N);

    // Load A (coalesced: lane t reads element (i, t) of each row i).
    for (int i = 0; i < N; ++i) A[i * S + t] = in[i * N + t];
    // Q_total = I
    for (int i = 0; i < N; ++i) Qt[i * S + t] = (i == t) ? 1.0f : 0.0f;
    __syncthreads();

    for (int iter = 0; iter < MAX_ITER; ++iter) {
        // Q = I
        for (int i = 0; i < N; ++i) Q[i * S + t] = (i == t) ? 1.0f : 0.0f;
        __syncthreads();

        // ---- Householder QR: A -> R (upper), Q accumulates H0*H1*...*H62 ----
        for (int k = 0; k < N - 1; ++k) {
            // x = A[k:, k] (lane = row)
            float x = (t >= k) ? A[t * S + k] : 0.0f;
            float ss = x * x;
            #pragma unroll
            for (int off = 32; off > 0; off >>= 1) ss += __shfl_xor(ss, off, 64);
            const float x0 = __shfl(x, k, 64);
            const float nrm = sqrtf(ss);
            const float alpha = (x0 >= 0.0f) ? -nrm : nrm;
            const float v0 = x0 - alpha;
            const float vtv = ss - x0 * x0 + v0 * v0;  // ||v||^2
            const float beta = (vtv > 1e-30f) ? 2.0f / vtv : 0.0f;
            v[t] = (t == k) ? v0 : x;  // x==0 for t<k
            __syncthreads();

            // A[:, j] update (thread t = column j >= k):  a -= beta*(v.a)*v
            if (t >= k) {
                float dot = 0.0f;
                #pragma unroll 4
                for (int i = k; i < N; ++i) dot += v[i] * A[i * S + t];
                const float c = beta * dot;
                #pragma unroll 4
                for (int i = k; i < N; ++i) A[i * S + t] -= c * v[i];
            }
            // Q row update (thread t = row r): Q[r, k:] -= beta*(Q[r,k:].v)*v
            {
                float dq = 0.0f;
                #pragma unroll 4
                for (int j = k; j < N; ++j) dq += Q[t * S + j] * v[j];
                const float c = beta * dq;
                #pragma unroll 4
                for (int j = k; j < N; ++j) Q[t * S + j] -= c * v[j];
            }
            __syncthreads();
        }

        // ---- Qt_new = Qt * Q (thread t owns output column t) ----
        float tmp[N];
        #pragma unroll
        for (int i = 0; i < N; ++i) {
            float acc = 0.0f;
            #pragma unroll 4
            for (int l = 0; l < N; ++l) acc += Qt[i * S + l] * Q[l * S + t];
            tmp[i] = acc;
        }
        __syncthreads();  // all threads done reading Qt
        #pragma unroll
        for (int i = 0; i < N; ++i) Qt[i * S + t] = tmp[i];

        // ---- A_next = R * Q (R = upper part of A; thread t owns column t) ----
        #pragma unroll
        for (int i = 0; i < N; ++i) {
            float acc = 0.0f;
            #pragma unroll 4
            for (int l = i; l < N; ++l) acc += A[i * S + l] * Q[l * S + t];
            tmp[i] = acc;
        }
        __syncthreads();  // all threads done reading A (and Qt writes drained)
        #pragma unroll
        for (int i = 0; i < N; ++i) A[i * S + t] = tmp[i];
        __syncthreads();
    }

    // ---- Epilogue: s = diag(A); sm = log(clip(s, EPS)); X = (U*sm) U^T ----
    {
        const float d = A[t * S + t];
        sm[t] = logf(fmaxf(d, 1e-6f));
    }
    __syncthreads();
    // W = U * diag(sm) into Q buffer (column t scaled by sm[t])
    {
        const float s_t = sm[t];
        for (int i = 0; i < N; ++i) Q[i * S + t] = Qt[i * S + t] * s_t;
    }
    __syncthreads();
    // X[i][j] = sum_l W[i][l] * U[j][l]; thread t = column j, coalesced row writes
    for (int i = 0; i < N; ++i) {
        float acc = 0.0f;
        #pragma unroll 4
        for (int l = 0; l < N; ++l) acc += Q[i * S + l] * Qt[t * S + l];
        out[i * N + t] = acc;
    }
}

extern "C" void kernel_launch(void* const* d_in, const int* in_sizes, int n_in,
                              void* d_out, int out_size, void* d_ws, size_t ws_size,
                              hipStream_t stream) {
    const float* in = (const float*)d_in[0];
    float* out = (float*)d_out;
    const int batch = in_sizes[0] / (N * N);
    hipLaunchKernelGGL(logm_kernel, dim3(batch), dim3(64), 0, stream, in, out);
}

// Round 2
// 3051.579 us; speedup vs baseline: 2.8409x; 2.8409x over previous
//
#include <hip/hip_runtime.h>
#include <math.h>

#define N 64
#define MS 68          // LDS column stride in floats: 16B-aligned float4s, 2-way banks (free)
#define MAX_ITER 5

// Broadcast lane `lane`'s value of x to all lanes (uniform lane -> v_readlane -> SGPR).
__device__ __forceinline__ float rl(float x, int lane) {
    return __uint_as_float(__builtin_amdgcn_readlane(__float_as_uint(x), lane));
}

// One 64-thread wave per 64x64 SPD matrix. Phase 1: Householder QR with A columns
// in registers (lane t = column t), Q_total rows in registers (lane t = row t),
// pivot-column broadcasts via readlane. Phase 2: one LDS transpose, then apply
// reflectors from the right to R's rows (A_next = R*Q). A_k symmetric => rows of
// A_next feed next iteration's columns directly.
__global__ __launch_bounds__(64, 2) void logm_kernel(const float* __restrict__ gin,
                                                     float* __restrict__ gout) {
    __shared__ __align__(16) float M[N * MS];

    const int t = threadIdx.x;
    const long b = blockIdx.x;
    const float* __restrict__ in = gin + b * (long)(N * N);
    float* __restrict__ out = gout + b * (long)(N * N);

    float a[N];   // phase 1: column t of A (upper->R, lower->v storage); phase 2: row t
    float qt[N];  // row t of Q_total
    float vv[N];  // phase 2: current reflector v_k (uniform values); epilogue: w

    // Coalesced exact column load (lane t reads element (i, t)).
    #pragma unroll
    for (int i = 0; i < N; ++i) a[i] = in[i * N + t];
    #pragma unroll
    for (int i = 0; i < N; ++i) qt[i] = (i == t) ? 1.0f : 0.0f;

    float betaS = 0.0f, v0S = 0.0f;  // lane k stashes beta_k / v0_k

    for (int iter = 0; iter < MAX_ITER; ++iter) {
        // ---------------- Phase 1: QR factorization + Qt := Qt*H_k ----------------
        for (int k = 0; k < N - 1; ++k) {
            // Sweep 1: ss = ||A[k:, k]||^2 and x0 = A[k][k]  (all lanes redundantly)
            float ss0 = 0.f, ss1 = 0.f, x0 = 0.f;
            #pragma unroll
            for (int i0 = 0; i0 < N; i0 += 8) {
                if (i0 + 8 > k) {                 // uniform branch: skip dead blocks
                    #pragma unroll
                    for (int u = 0; u < 8; ++u) {
                        const int i = i0 + u;
                        float xi = rl(a[i], k);
                        xi = (i >= k) ? xi : 0.0f;            // uniform select
                        if (u & 1) ss1 = fmaf(xi, xi, ss1);
                        else       ss0 = fmaf(xi, xi, ss0);
                        x0 = (i == k) ? xi : x0;              // uniform capture
                    }
                }
            }
            const float ss = ss0 + ss1;
            const float nrm = sqrtf(ss);
            const float alpha = (x0 >= 0.0f) ? -nrm : nrm;
            const float v0 = x0 - alpha;
            const float vtv = fmaf(v0, v0, ss - x0 * x0);     // ||v||^2
            const float beta = (vtv > 1e-30f) ? 2.0f / vtv : 0.0f;
            betaS = (t == k) ? beta : betaS;
            v0S   = (t == k) ? v0   : v0S;

            // Sweep 2: dota = v . A[:,t], dotq = Qt[t,:] . v   (coef ci is uniform)
            float da0 = 0.f, da1 = 0.f, dq0 = 0.f, dq1 = 0.f;
            #pragma unroll
            for (int i0 = 0; i0 < N; i0 += 8) {
                if (i0 + 8 > k) {
                    #pragma unroll
                    for (int u = 0; u < 8; ++u) {
                        const int i = i0 + u;
                        float ci = rl(a[i], k);
                        ci = (i > k) ? ci : ((i == k) ? v0 : 0.0f);
                        if (u & 1) { da1 = fmaf(ci, a[i], da1); dq1 = fmaf(ci, qt[i], dq1); }
                        else       { da0 = fmaf(ci, a[i], da0); dq0 = fmaf(ci, qt[i], dq0); }
                    }
                }
            }
            const float ca = beta * (da0 + da1);
            const float cq = beta * (dq0 + dq1);
            const float caEff = (t > k) ? ca : 0.0f;  // lanes <= k: column frozen / special

            // Sweep 3: A[:,t] -= caEff*v ; Qt[t,:] -= cq*v ; lane k finalizes column k
            #pragma unroll
            for (int i0 = 0; i0 < N; i0 += 8) {
                if (i0 + 8 > k) {
                    #pragma unroll
                    for (int u = 0; u < 8; ++u) {
                        const int i = i0 + u;
                        float ci = rl(a[i], k);
                        ci = (i > k) ? ci : ((i == k) ? v0 : 0.0f);
                        a[i]  = fmaf(-caEff, ci, a[i]);
                        qt[i] = fmaf(-cq,    ci, qt[i]);
                        if (i == k) a[i] = (t == k) ? alpha : a[i];  // R diag; lane k keeps v below
                    }
                }
            }
        }

        // ---------------- Phase 2: A_next = R * H0 * ... * H62 (row-local) ----------------
        __syncthreads();  // previous iteration's M readers are done (no-op on iter 0)
        #pragma unroll
        for (int i = 0; i < N; i += 4) {   // write column t (contiguous per lane, b128)
            float4 w4;
            w4.x = a[i]; w4.y = a[i + 1]; w4.z = a[i + 2]; w4.w = a[i + 3];
            *reinterpret_cast<float4*>(&M[t * MS + i]) = w4;
        }
        __syncthreads();
        #pragma unroll
        for (int j = 0; j < N; ++j) a[j] = M[j * MS + t];       // row t of (R + V-storage)
        #pragma unroll
        for (int j = 0; j < N; ++j) a[j] = (j >= t) ? a[j] : 0.0f;  // true R row

        for (int k = 0; k < N - 1; ++k) {
            const float bk  = rl(betaS, k);
            const float v0k = rl(v0S, k);
            float d0 = 0.f, d1 = 0.f;
            #pragma unroll
            for (int j0 = 0; j0 < N; j0 += 8) {
                if (j0 + 8 > k) {
                    // v_k[j] = M[k*MS + j] : uniform-address broadcast float4 loads
                    float4 p = *reinterpret_cast<const float4*>(&M[k * MS + j0]);
                    float4 q = *reinterpret_cast<const float4*>(&M[k * MS + j0 + 4]);
                    vv[j0 + 0] = p.x; vv[j0 + 1] = p.y; vv[j0 + 2] = p.z; vv[j0 + 3] = p.w;
                    vv[j0 + 4] = q.x; vv[j0 + 5] = q.y; vv[j0 + 6] = q.z; vv[j0 + 7] = q.w;
                    #pragma unroll
                    for (int u = 0; u < 8; ++u) {
                        const int j = j0 + u;
                        float cj = (j > k) ? vv[j] : ((j == k) ? v0k : 0.0f);
                        vv[j] = cj;                       // keep selected coef for update
                        if (u & 1) d1 = fmaf(cj, a[j], d1);
                        else       d0 = fmaf(cj, a[j], d0);
                    }
                }
            }
            const float c = bk * (d0 + d1);
            #pragma unroll
            for (int j0 = 0; j0 < N; j0 += 8) {
                if (j0 + 8 > k) {
                    #pragma unroll
                    for (int u = 0; u < 8; ++u) {
                        const int j = j0 + u;
                        a[j] = fmaf(-c, vv[j], a[j]);
                    }
                }
            }
        }
        // a[] now holds row t of A_next == column t (A_next symmetric up to rounding)
    }

    // ---------------- Epilogue: X = U * diag(log(clip(diag(A),eps))) * U^T ----------------
    #pragma unroll
    for (int l = 0; l < N; ++l) {
        const float dl = rl(a[l], l);                 // A[l][l] (uniform)
        const float sml = __logf(fmaxf(dl, 1e-6f));
        vv[l] = sml * qt[l];                          // w[l] = sm[l] * U[t][l]
    }
    for (int i = 0; i < N; ++i) {                     // output row i; lane t = column
        float acc0 = 0.f, acc1 = 0.f;
        #pragma unroll
        for (int l = 0; l < N; l += 2) {
            acc0 = fmaf(rl(vv[l],     i), qt[l],     acc0);  // sm[l]*U[i][l]*U[t][l]
            acc1 = fmaf(rl(vv[l + 1], i), qt[l + 1], acc1);
        }
        out[i * N + t] = acc0 + acc1;
    }
}

extern "C" void kernel_launch(void* const* d_in, const int* in_sizes, int n_in,
                              void* d_out, int out_size, void* d_ws, size_t ws_size,
                              hipStream_t stream) {
    const float* in = (const float*)d_in[0];
    float* out = (float*)d_out;
    const int batch = in_sizes[0] / (N * N);
    hipLaunchKernelGGL(logm_kernel, dim3(batch), dim3(64), 0, stream, in, out);
}

// Round 3
// 2004.410 us; speedup vs baseline: 4.3251x; 1.5224x over previous
//
#include <hip/hip_runtime.h>
#include <math.h>

#define N 64
#define GS 68   // LDS row stride (floats): 272 B = 17*16 B -> b128-aligned rows; col reads conflict-free
#define MAX_ITER 5

__device__ __forceinline__ float rl(float x, int lane) {
    return __uint_as_float(__builtin_amdgcn_readlane(__float_as_uint(x), lane));
}

// One 64-thread wave per 64x64 SPD matrix, barrier-free (single-wave LDS is in-order).
// Phase 1: Householder QR, lane t = column t. At step k lane k archives its column to
// LDS row k (builds F^T incrementally = the phase-2 transpose + persistent v_k storage).
// Coefficients come back as uniform-address b128 broadcasts; selects only in the one
// boundary 8-block. Next pivot norm accumulated inside the update pass.
// Phase 2: lane t = row t of A_next = R*H0..H62 (A symmetric => rows feed next iter's cols).
__global__ __launch_bounds__(64, 2) void logm_kernel(const float* __restrict__ gin,
                                                     float* __restrict__ gout) {
    __shared__ __align__(16) float G[N * GS];
    const int t = threadIdx.x;
    const long b = blockIdx.x;
    const float* __restrict__ in = gin + b * (long)(N * N);
    float* __restrict__ out = gout + b * (long)(N * N);

    float a[N];   // phase 1: column t; phase 2: row t
    float qt[N];  // row t of Q_total

    #pragma unroll
    for (int i = 0; i < N; ++i) a[i] = in[i * N + t];
    #pragma unroll
    for (int i = 0; i < N; ++i) qt[i] = (i == t) ? 1.0f : 0.0f;

    float betaS = 0.0f, v0S = 0.0f;  // lane k stashes beta_k / v0_k for phase 2

    for (int iter = 0; iter < MAX_ITER; ++iter) {
        // Seed pivot-column norm for k=0 (lane 0's value is the one consumed).
        float s0 = 0.f, s1 = 0.f;
        #pragma unroll
        for (int i = 0; i < N; i += 2) { s0 = fmaf(a[i], a[i], s0); s1 = fmaf(a[i+1], a[i+1], s1); }
        float ssn = s0 + s1;

        for (int k = 0; k < N - 1; ++k) {
            // Archive current column k -> G row k (R upper part + v_k tail; diag patched below).
            if (t == k) {
                #pragma unroll
                for (int i = 0; i < N; i += 4) {
                    float4 w; w.x = a[i]; w.y = a[i+1]; w.z = a[i+2]; w.w = a[i+3];
                    *reinterpret_cast<float4*>(&G[k * GS + i]) = w;
                }
            }
            const float ss = rl(ssn, k);
            const float x0 = G[k * GS + k];              // uniform broadcast read (in-order after write)
            const float nrm = sqrtf(ss);
            const float alpha = (x0 >= 0.f) ? -nrm : nrm;
            const float v0 = x0 - alpha;
            const float vtv = fmaf(v0, v0, ss - x0 * x0);
            const float beta = (vtv > 1e-30f) ? __fdividef(2.0f, vtv) : 0.f;
            betaS = (t == k) ? beta : betaS;
            v0S   = (t == k) ? v0   : v0S;
            if (t == k) G[k * GS + k] = alpha;           // R diagonal for phase 2

            const int B0 = k & ~7;

            // Pass B: da = v . A[:,t]  (all lanes),  dq = Qt[t,:] . v
            float da0 = 0.f, da1 = 0.f, dq0 = 0.f, dq1 = 0.f;
            #pragma unroll
            for (int i0 = 0; i0 < N; i0 += 8) {
                if (i0 + 8 > k) {                         // uniform skip of dead blocks
                    float4 c0 = *reinterpret_cast<const float4*>(&G[k * GS + i0]);
                    float4 c1 = *reinterpret_cast<const float4*>(&G[k * GS + i0 + 4]);
                    float c[8] = {c0.x, c0.y, c0.z, c0.w, c1.x, c1.y, c1.z, c1.w};
                    if (i0 == B0) {                       // boundary block: patch coefficients
                        #pragma unroll
                        for (int u = 0; u < 8; ++u) {
                            const int i = i0 + u;
                            c[u] = (i > k) ? c[u] : ((i == k) ? v0 : 0.f);
                        }
                    }
                    #pragma unroll
                    for (int u = 0; u < 8; ++u) {
                        const int i = i0 + u;
                        if (u & 1) { da1 = fmaf(c[u], a[i], da1); dq1 = fmaf(c[u], qt[i], dq1); }
                        else       { da0 = fmaf(c[u], a[i], da0); dq0 = fmaf(c[u], qt[i], dq0); }
                    }
                }
            }
            const float ca  = beta * (da0 + da1);
            const float cq  = beta * (dq0 + dq1);
            const float caE = (t > k) ? ca : 0.f;         // freeze columns <= k

            // Pass C: update A-columns and Qt-rows; accumulate next pivot-column norm.
            float sn0 = 0.f, sn1 = 0.f;
            #pragma unroll
            for (int i0 = 0; i0 < N; i0 += 8) {
                if (i0 + 8 > k) {
                    float4 c0 = *reinterpret_cast<const float4*>(&G[k * GS + i0]);
                    float4 c1 = *reinterpret_cast<const float4*>(&G[k * GS + i0 + 4]);
                    float c[8] = {c0.x, c0.y, c0.z, c0.w, c1.x, c1.y, c1.z, c1.w};
                    if (i0 == B0) {
                        #pragma unroll
                        for (int u = 0; u < 8; ++u) {
                            const int i = i0 + u;
                            c[u] = (i > k) ? c[u] : ((i == k) ? v0 : 0.f);
                        }
                    }
                    #pragma unroll
                    for (int u = 0; u < 8; ++u) {
                        const int i = i0 + u;
                        a[i]  = fmaf(-caE, c[u], a[i]);
                        qt[i] = fmaf(-cq,  c[u], qt[i]);
                        float av = a[i];
                        if (i0 == B0) av = (i > k) ? av : 0.f;   // only i>k counts toward ss_{k+1}
                        if (u & 1) sn1 = fmaf(av, av, sn1); else sn0 = fmaf(av, av, sn0);
                    }
                }
            }
            ssn = sn0 + sn1;
        }

        // Archive final column 63 (post H_62).
        if (t == N - 1) {
            #pragma unroll
            for (int i = 0; i < N; i += 4) {
                float4 w; w.x = a[i]; w.y = a[i+1]; w.z = a[i+2]; w.w = a[i+3];
                *reinterpret_cast<float4*>(&G[(N - 1) * GS + i]) = w;
            }
        }

        // ---- Phase 2: a[] <- row t of R (mask strict lower), then A_next = R*H0..H62 ----
        #pragma unroll
        for (int j = 0; j < N; ++j) {
            const float rj = G[j * GS + t];               // per-lane column read, conflict-free
            a[j] = (j >= t) ? rj : 0.f;
        }

        for (int k = 0; k < N - 1; ++k) {
            const float bk  = rl(betaS, k);
            const float v0k = rl(v0S, k);
            const int B0 = k & ~7;
            float d0 = 0.f, d1 = 0.f, d2 = 0.f, d3 = 0.f;
            #pragma unroll
            for (int j0 = 0; j0 < N; j0 += 8) {
                if (j0 + 8 > k) {
                    float4 c0 = *reinterpret_cast<const float4*>(&G[k * GS + j0]);
                    float4 c1 = *reinterpret_cast<const float4*>(&G[k * GS + j0 + 4]);
                    float c[8] = {c0.x, c0.y, c0.z, c0.w, c1.x, c1.y, c1.z, c1.w};
                    if (j0 == B0) {
                        #pragma unroll
                        for (int u = 0; u < 8; ++u) {
                            const int j = j0 + u;
                            c[u] = (j > k) ? c[u] : ((j == k) ? v0k : 0.f);
                        }
                    }
                    #pragma unroll
                    for (int u = 0; u < 8; ++u) {
                        const int j = j0 + u;
                        if      ((u & 3) == 0) d0 = fmaf(c[u], a[j], d0);
                        else if ((u & 3) == 1) d1 = fmaf(c[u], a[j], d1);
                        else if ((u & 3) == 2) d2 = fmaf(c[u], a[j], d2);
                        else                   d3 = fmaf(c[u], a[j], d3);
                    }
                }
            }
            const float cc = bk * ((d0 + d1) + (d2 + d3));
            #pragma unroll
            for (int j0 = 0; j0 < N; j0 += 8) {
                if (j0 + 8 > k) {
                    float4 c0 = *reinterpret_cast<const float4*>(&G[k * GS + j0]);
                    float4 c1 = *reinterpret_cast<const float4*>(&G[k * GS + j0 + 4]);
                    float c[8] = {c0.x, c0.y, c0.z, c0.w, c1.x, c1.y, c1.z, c1.w};
                    if (j0 == B0) {
                        #pragma unroll
                        for (int u = 0; u < 8; ++u) {
                            const int j = j0 + u;
                            c[u] = (j > k) ? c[u] : ((j == k) ? v0k : 0.f);
                        }
                    }
                    #pragma unroll
                    for (int u = 0; u < 8; ++u) {
                        const int j = j0 + u;
                        a[j] = fmaf(-cc, c[u], a[j]);
                    }
                }
            }
        }
        // a[] = row t of A_next = column t (symmetric) -> feeds next iteration directly.
    }

    // ---- Epilogue: sm = log(clip(diag)), w = sm .* U-row (into a[]), X = w . U^T ----
    #pragma unroll
    for (int l = 0; l < N; ++l) {
        const float dl = __shfl(a[l], l, 64);             // A[l][l]
        const float sml = __logf(fmaxf(dl, 1e-6f));
        a[l] = sml * qt[l];                               // w[l] = sm[l] * U[t][l]
    }
    #pragma unroll
    for (int l = 0; l < N; l += 4) {                      // U rows -> G (overwrite factored matrix)
        float4 w; w.x = qt[l]; w.y = qt[l+1]; w.z = qt[l+2]; w.w = qt[l+3];
        *reinterpret_cast<float4*>(&G[t * GS + l]) = w;
    }
    #pragma unroll 2
    for (int j = 0; j < N; ++j) {                         // X[t][j]; store at [j][t] (X symmetric)
        float e0 = 0.f, e1 = 0.f, e2 = 0.f, e3 = 0.f;
        #pragma unroll
        for (int l = 0; l < N; l += 4) {
            float4 u4 = *reinterpret_cast<const float4*>(&G[j * GS + l]);
            e0 = fmaf(a[l+0], u4.x, e0);
            e1 = fmaf(a[l+1], u4.y, e1);
            e2 = fmaf(a[l+2], u4.z, e2);
            e3 = fmaf(a[l+3], u4.w, e3);
        }
        out[j * N + t] = (e0 + e1) + (e2 + e3);           // coalesced
    }
}

extern "C" void kernel_launch(void* const* d_in, const int* in_sizes, int n_in,
                              void* d_out, int out_size, void* d_ws, size_t ws_size,
                              hipStream_t stream) {
    const float* in = (const float*)d_in[0];
    float* out = (float*)d_out;
    const int batch = in_sizes[0] / (N * N);
    hipLaunchKernelGGL(logm_kernel, dim3(batch), dim3(64), 0, stream, in, out);
}